// Round 5
// baseline (107.735 us; speedup 1.0000x reference)
//
#include <hip/hip_runtime.h>
#include <cmath>

#define HID 1024
#define OUTN 512
#define VOCABN 1024
#define MSIZE 262144
#define MDIM 128

// ws float layout
#define WS_H 0   // [1024] h

__device__ __forceinline__ float wred64(float v) {
#pragma unroll
    for (int m = 32; m; m >>= 1) v += __shfl_xor(v, m, 64);
    return v;
}

__device__ __forceinline__ float dot4(const float4* __restrict__ a,
                                      const float4* __restrict__ b,
                                      int n4, int lane) {
    float acc = 0.f;
    for (int k = lane; k < n4; k += 64) {
        float4 x = a[k], y = b[k];
        acc = fmaf(x.x, y.x, fmaf(x.y, y.y, fmaf(x.z, y.z, fmaf(x.w, y.w, acc))));
    }
    return wred64(acc);
}

__device__ __forceinline__ float4 blend4(float aw0, float aw1, float4 push, float4 pop) {
    float4 r;
    r.x = fmaf(aw0, push.x, aw1 * pop.x);
    r.y = fmaf(aw0, push.y, aw1 * pop.y);
    r.z = fmaf(aw0, push.z, aw1 * pop.z);
    r.w = fmaf(aw0, push.w, aw1 * pop.w);
    return r;
}

// Kernel 1: hidden_bar (per-block redundant, LDS) then h = tanh(...)
// 128 blocks x 512 threads; 8 rows of h per block (1 wave per row).
__global__ __launch_bounds__(512) void k_h(
    const float* __restrict__ input, const float* __restrict__ hidden0,
    const float* __restrict__ stack, const float* __restrict__ W_ih,
    const float* __restrict__ W_hh, const float* __restrict__ b_ih,
    const float* __restrict__ b_hh, const float* __restrict__ W_sh,
    const float* __restrict__ b_sh, float* __restrict__ ws,
    float* __restrict__ d_out) {
    __shared__ float hb[HID];
    const int tid  = threadIdx.x;
    const int lane = tid & 63;
    const int wave = tid >> 6;   // 0..7
    const int sub  = lane & 31;
    const int half = lane >> 5;

    // phase 1: hidden_bar[row] = W_sh[row,:]·stack[0,:] + b_sh[row] + hidden0[row]
    const float4 sv = ((const float4*)stack)[sub];
    const float4* Wsh4 = (const float4*)W_sh;
    for (int i = 0; i < 64; ++i) {
        const int row = i * 16 + wave * 2 + half;
        const float4 w4 = Wsh4[row * 32 + sub];
        float a = fmaf(w4.x, sv.x, fmaf(w4.y, sv.y, fmaf(w4.z, sv.z, w4.w * sv.w)));
#pragma unroll
        for (int m = 16; m; m >>= 1) a += __shfl_xor(a, m, 64);
        if (sub == 0) hb[row] = a + b_sh[row] + hidden0[row];
    }
    __syncthreads();

    // phase 2: h[R] = tanh(W_ih[R]·input + W_hh[R]·hb + b_ih[R] + b_hh[R])
    const int R = blockIdx.x * 8 + wave;
    const float4* wi  = (const float4*)(W_ih + R * VOCABN);
    const float4* wh  = (const float4*)(W_hh + R * HID);
    const float4* in4 = (const float4*)input;
    const float4* hb4 = (const float4*)hb;
    float acc = 0.f;
    for (int k = lane; k < VOCABN / 4; k += 64) {
        float4 a = wi[k], b = in4[k];
        acc = fmaf(a.x, b.x, fmaf(a.y, b.y, fmaf(a.z, b.z, fmaf(a.w, b.w, acc))));
        float4 c = wh[k], d = hb4[k];
        acc = fmaf(c.x, d.x, fmaf(c.y, d.y, fmaf(c.z, d.z, fmaf(c.w, d.w, acc))));
    }
    acc = wred64(acc);
    if (lane == 0) {
        const float h = tanhf(acc + b_ih[R] + b_hh[R]);
        ws[WS_H + R] = h;
        d_out[OUTN + R] = h;
    }
}

// Kernel 2: heads + blend, NO cross-block sync, branchless interior blend.
// 2048 blocks x 256 threads; block b blends contiguous float4s [b*4096, (b+1)*4096).
__global__ __launch_bounds__(256) void k_mega(
    const float* __restrict__ stack, const float* __restrict__ W_y,
    const float* __restrict__ b_y, const float* __restrict__ W_n,
    const float* __restrict__ b_n, const float* __restrict__ W_a,
    const float* __restrict__ b_a, const float* __restrict__ ws,
    float* __restrict__ d_out) {
    __shared__ float s_aw[2];
    __shared__ __align__(16) float s_ne[MDIM];
    const int b    = blockIdx.x;
    const int tid  = threadIdx.x;
    const int lane = tid & 63;
    const int wave = tid >> 6;   // 0..3
    const float4* h4 = (const float4*)(ws + WS_H);

    // redundant action softmax (wave 0)
    if (wave == 0) {
        float l0 = dot4((const float4*)W_a,         h4, HID / 4, lane);
        float l1 = dot4((const float4*)(W_a + HID), h4, HID / 4, lane);
        if (lane == 0) {
            l0 += b_a[0];
            l1 += b_a[1];
            const float mx = fmaxf(l0, l1);
            const float e0 = expf(l0 - mx), e1 = expf(l1 - mx);
            const float s = e0 + e1;
            s_aw[0] = e0 / s;
            s_aw[1] = e1 / s;
        }
    }

    // block 0: new_elt (128 rows), 4 waves x 32 rows, 4 rows at a time for ILP
    if (b == 0) {
        for (int g = 0; g < 32; g += 4) {
            const int m = wave * 32 + g;
            const float4* r0 = (const float4*)(W_n + (m + 0) * HID);
            const float4* r1 = (const float4*)(W_n + (m + 1) * HID);
            const float4* r2 = (const float4*)(W_n + (m + 2) * HID);
            const float4* r3 = (const float4*)(W_n + (m + 3) * HID);
            float a0 = 0.f, a1 = 0.f, a2 = 0.f, a3 = 0.f;
            for (int k = lane; k < HID / 4; k += 64) {
                const float4 hv = h4[k];
                const float4 w0 = r0[k], w1 = r1[k], w2 = r2[k], w3 = r3[k];
                a0 = fmaf(w0.x, hv.x, fmaf(w0.y, hv.y, fmaf(w0.z, hv.z, fmaf(w0.w, hv.w, a0))));
                a1 = fmaf(w1.x, hv.x, fmaf(w1.y, hv.y, fmaf(w1.z, hv.z, fmaf(w1.w, hv.w, a1))));
                a2 = fmaf(w2.x, hv.x, fmaf(w2.y, hv.y, fmaf(w2.z, hv.z, fmaf(w2.w, hv.w, a2))));
                a3 = fmaf(w3.x, hv.x, fmaf(w3.y, hv.y, fmaf(w3.z, hv.z, fmaf(w3.w, hv.w, a3))));
            }
            a0 = wred64(a0); a1 = wred64(a1); a2 = wred64(a2); a3 = wred64(a3);
            if (lane == 0) {
                s_ne[m + 0] = 1.f / (1.f + expf(-(a0 + b_n[m + 0])));
                s_ne[m + 1] = 1.f / (1.f + expf(-(a1 + b_n[m + 1])));
                s_ne[m + 2] = 1.f / (1.f + expf(-(a2 + b_n[m + 2])));
                s_ne[m + 3] = 1.f / (1.f + expf(-(a3 + b_n[m + 3])));
            }
        }
    }
    __syncthreads();

    const float aw0 = s_aw[0];
    const float aw1 = s_aw[1];

    const float4* s4  = (const float4*)stack;
    float4* o4 = (float4*)(d_out + OUTN + HID);
    const int base = b * 4096;
    const int total4 = MSIZE * (MDIM / 4);

    if (b == 0) {
        // first 32 float4s (stack row 0): push from LDS new_elt
        const float4* ne4 = (const float4*)s_ne;
        for (int it = 0; it < 16; ++it) {
            const int e = it * 256 + tid;
            float4 push;
            if (e < 32) push = ne4[e];
            else        push = s4[e - 32];
            const float4 pop = s4[e + 32];
            o4[e] = blend4(aw0, aw1, push, pop);
        }
    } else if (b == 2047) {
        // last 32 float4s (stack row MSIZE-1): pop = 0
        for (int it = 0; it < 16; ++it) {
            const int e = base + it * 256 + tid;
            const float4 push = s4[e - 32];
            float4 pop;
            if (e < total4 - 32) pop = s4[e + 32];
            else                 pop = make_float4(0.f, 0.f, 0.f, 0.f);
            o4[e] = blend4(aw0, aw1, push, pop);
        }
    } else {
        // interior: fully branchless stream
        const float4* pu = s4 + base - 32;
        const float4* po = s4 + base + 32;
        float4* ob = o4 + base;
#pragma unroll 8
        for (int it = 0; it < 16; ++it) {
            const int i = it * 256 + tid;
            const float4 push = pu[i];
            const float4 pop  = po[i];
            ob[i] = blend4(aw0, aw1, push, pop);
        }
    }

    // output head tail: blocks 1..512, wave 0, one row each
    if (b >= 1 && b <= OUTN && wave == 0) {
        const int r = b - 1;
        const float a = dot4((const float4*)(W_y + r * HID), h4, HID / 4, lane);
        if (lane == 0) d_out[r] = 1.f / (1.f + expf(-(a + b_y[r])));
    }
}

extern "C" void kernel_launch(void* const* d_in, const int* in_sizes, int n_in,
                              void* d_out, int out_size, void* d_ws, size_t ws_size,
                              hipStream_t stream) {
    const float* input   = (const float*)d_in[0];
    const float* hidden0 = (const float*)d_in[1];
    const float* stack   = (const float*)d_in[2];
    const float* W_ih    = (const float*)d_in[3];
    const float* W_hh    = (const float*)d_in[4];
    const float* b_ih    = (const float*)d_in[5];
    const float* b_hh    = (const float*)d_in[6];
    const float* W_y     = (const float*)d_in[7];
    const float* b_y     = (const float*)d_in[8];
    const float* W_n     = (const float*)d_in[9];
    const float* b_n     = (const float*)d_in[10];
    const float* W_a     = (const float*)d_in[11];
    const float* b_a     = (const float*)d_in[12];
    const float* W_sh    = (const float*)d_in[13];
    const float* b_sh    = (const float*)d_in[14];
    float* out = (float*)d_out;
    float* ws  = (float*)d_ws;

    k_h<<<128, 512, 0, stream>>>(input, hidden0, stack, W_ih, W_hh,
                                 b_ih, b_hh, W_sh, b_sh, ws, out);
    k_mega<<<2048, 256, 0, stream>>>(stack, W_y, b_y, W_n, b_n, W_a, b_a, ws, out);
}

// Round 6
// 104.385 us; speedup vs baseline: 1.0321x; 1.0321x over previous
//
#include <hip/hip_runtime.h>
#include <cmath>

#define HID 1024
#define OUTN 512
#define VOCABN 1024
#define MSIZE 262144
#define MDIM 128

// ws float layout
#define WS_H  0     // [1024] h
#define WS_AW 1024  // [2]    action weights
#define WS_NE 1040  // [128]  new_elt (1040*4=4160, 16B aligned)

__device__ __forceinline__ float wred64(float v) {
#pragma unroll
    for (int m = 32; m; m >>= 1) v += __shfl_xor(v, m, 64);
    return v;
}

__device__ __forceinline__ float dot4(const float4* __restrict__ a,
                                      const float4* __restrict__ b,
                                      int n4, int lane) {
    float acc = 0.f;
    for (int k = lane; k < n4; k += 64) {
        float4 x = a[k], y = b[k];
        acc = fmaf(x.x, y.x, fmaf(x.y, y.y, fmaf(x.z, y.z, fmaf(x.w, y.w, acc))));
    }
    return wred64(acc);
}

// Kernel 1: hidden_bar (per-block redundant, LDS) then h = tanh(...)
__global__ __launch_bounds__(512) void k_h(
    const float* __restrict__ input, const float* __restrict__ hidden0,
    const float* __restrict__ stack, const float* __restrict__ W_ih,
    const float* __restrict__ W_hh, const float* __restrict__ b_ih,
    const float* __restrict__ b_hh, const float* __restrict__ W_sh,
    const float* __restrict__ b_sh, float* __restrict__ ws,
    float* __restrict__ d_out) {
    __shared__ float hb[HID];
    const int tid  = threadIdx.x;
    const int lane = tid & 63;
    const int wave = tid >> 6;   // 0..7
    const int sub  = lane & 31;
    const int half = lane >> 5;

    const float4 sv = ((const float4*)stack)[sub];
    const float4* Wsh4 = (const float4*)W_sh;
    for (int i = 0; i < 64; ++i) {
        const int row = i * 16 + wave * 2 + half;
        const float4 w4 = Wsh4[row * 32 + sub];
        float a = fmaf(w4.x, sv.x, fmaf(w4.y, sv.y, fmaf(w4.z, sv.z, w4.w * sv.w)));
#pragma unroll
        for (int m = 16; m; m >>= 1) a += __shfl_xor(a, m, 64);
        if (sub == 0) hb[row] = a + b_sh[row] + hidden0[row];
    }
    __syncthreads();

    const int R = blockIdx.x * 8 + wave;
    const float4* wi  = (const float4*)(W_ih + R * VOCABN);
    const float4* wh  = (const float4*)(W_hh + R * HID);
    const float4* in4 = (const float4*)input;
    const float4* hb4 = (const float4*)hb;
    float acc = 0.f;
    for (int k = lane; k < VOCABN / 4; k += 64) {
        float4 a = wi[k], b = in4[k];
        acc = fmaf(a.x, b.x, fmaf(a.y, b.y, fmaf(a.z, b.z, fmaf(a.w, b.w, acc))));
        float4 c = wh[k], d = hb4[k];
        acc = fmaf(c.x, d.x, fmaf(c.y, d.y, fmaf(c.z, d.z, fmaf(c.w, d.w, acc))));
    }
    acc = wred64(acc);
    if (lane == 0) {
        const float h = tanhf(acc + b_ih[R] + b_hh[R]);
        ws[WS_H + R] = h;
        d_out[OUTN + R] = h;
    }
}

// Kernel 2: all heads. rows 0..511 -> output; 512..639 -> new_elt; 640 -> action softmax.
__global__ __launch_bounds__(256) void k_heads(
    const float* __restrict__ W_y, const float* __restrict__ b_y,
    const float* __restrict__ W_n, const float* __restrict__ b_n,
    const float* __restrict__ W_a, const float* __restrict__ b_a,
    float* __restrict__ ws, float* __restrict__ d_out) {
    const int lane = threadIdx.x & 63;
    const int row = blockIdx.x * (blockDim.x >> 6) + (threadIdx.x >> 6);
    const float4* h4 = (const float4*)(ws + WS_H);
    if (row < OUTN) {
        const float a = dot4((const float4*)(W_y + row * HID), h4, HID / 4, lane);
        if (lane == 0) d_out[row] = 1.f / (1.f + expf(-(a + b_y[row])));
    } else if (row < OUTN + MDIM) {
        const int m = row - OUTN;
        const float a = dot4((const float4*)(W_n + m * HID), h4, HID / 4, lane);
        if (lane == 0) ws[WS_NE + m] = 1.f / (1.f + expf(-(a + b_n[m])));
    } else if (row == OUTN + MDIM) {
        float l0 = dot4((const float4*)W_a,         h4, HID / 4, lane);
        float l1 = dot4((const float4*)(W_a + HID), h4, HID / 4, lane);
        if (lane == 0) {
            l0 += b_a[0];
            l1 += b_a[1];
            const float mx = fmaxf(l0, l1);
            const float e0 = expf(l0 - mx), e1 = expf(l1 - mx);
            const float s = e0 + e1;
            ws[WS_AW]     = e0 / s;
            ws[WS_AW + 1] = e1 / s;
        }
    }
}

// Kernel 3: pure blend, grid-stride interleaved (round-1 structure).
__global__ __launch_bounds__(256) void k_stack(
    const float* __restrict__ stack, const float* __restrict__ ws,
    float* __restrict__ out_stack) {
    const float aw0 = ws[WS_AW];
    const float aw1 = ws[WS_AW + 1];
    const float4* s4  = (const float4*)stack;
    const float4* ne4 = (const float4*)(ws + WS_NE);
    float4* o4 = (float4*)out_stack;
    const int total4 = MSIZE * (MDIM / 4);  // 8,388,608; 32 float4 per row
    for (int e = blockIdx.x * blockDim.x + threadIdx.x; e < total4;
         e += gridDim.x * blockDim.x) {
        const int row = e >> 5;
        float4 push, pop;
        if (row == 0) push = ne4[e & 31];
        else          push = s4[e - 32];
        if (row == MSIZE - 1) pop = make_float4(0.f, 0.f, 0.f, 0.f);
        else                  pop = s4[e + 32];
        float4 r;
        r.x = fmaf(aw0, push.x, aw1 * pop.x);
        r.y = fmaf(aw0, push.y, aw1 * pop.y);
        r.z = fmaf(aw0, push.z, aw1 * pop.z);
        r.w = fmaf(aw0, push.w, aw1 * pop.w);
        o4[e] = r;
    }
}

extern "C" void kernel_launch(void* const* d_in, const int* in_sizes, int n_in,
                              void* d_out, int out_size, void* d_ws, size_t ws_size,
                              hipStream_t stream) {
    const float* input   = (const float*)d_in[0];
    const float* hidden0 = (const float*)d_in[1];
    const float* stack   = (const float*)d_in[2];
    const float* W_ih    = (const float*)d_in[3];
    const float* W_hh    = (const float*)d_in[4];
    const float* b_ih    = (const float*)d_in[5];
    const float* b_hh    = (const float*)d_in[6];
    const float* W_y     = (const float*)d_in[7];
    const float* b_y     = (const float*)d_in[8];
    const float* W_n     = (const float*)d_in[9];
    const float* b_n     = (const float*)d_in[10];
    const float* W_a     = (const float*)d_in[11];
    const float* b_a     = (const float*)d_in[12];
    const float* W_sh    = (const float*)d_in[13];
    const float* b_sh    = (const float*)d_in[14];
    float* out = (float*)d_out;
    float* ws  = (float*)d_ws;

    k_h<<<128, 512, 0, stream>>>(input, hidden0, stack, W_ih, W_hh,
                                 b_ih, b_hh, W_sh, b_sh, ws, out);
    k_heads<<<161, 256, 0, stream>>>(W_y, b_y, W_n, b_n, W_a, b_a, ws, out);
    k_stack<<<2048, 256, 0, stream>>>(stack, ws, out + OUTN + HID);
}

// Round 7
// 73.084 us; speedup vs baseline: 1.4741x; 1.4283x over previous
//
#include <hip/hip_runtime.h>
#include <cmath>

#define HID 1024
#define OUTN 512
#define VOCABN 1024
#define MSIZE 262144
#define MDIM 128

// workspace layout (floats)
#define WS_TIH 0      // [1024] W_ih@input + b_ih
#define WS_HB  1024   // [1024] hidden_bar
#define WS_H   2048   // [1024] h
#define WS_AW  3072   // [2]    softmax action weights
#define WS_NE  3076   // [128]  new_elt (16B aligned: 3076*4 % 16 == 0)

__device__ __forceinline__ float wred(float v) {
#pragma unroll
    for (int m = 32; m; m >>= 1) v += __shfl_xor(v, m, 64);
    return v;
}

// wave-cooperative dot over n4 float4s (all 64 lanes participate; result in all lanes)
__device__ __forceinline__ float dot4(const float4* __restrict__ a,
                                      const float4* __restrict__ b,
                                      int n4, int lane) {
    float acc = 0.f;
    for (int k = lane; k < n4; k += 64) {
        float4 x = a[k], y = b[k];
        acc = fmaf(x.x, y.x, acc);
        acc = fmaf(x.y, y.y, acc);
        acc = fmaf(x.z, y.z, acc);
        acc = fmaf(x.w, y.w, acc);
    }
    return wred(acc);
}

// Kernel A: t_ih[row] = W_ih[row,:]·input + b_ih[row]
//           hidden_bar[row] = W_sh[row,:]·stack[0,:] + b_sh[row] + hidden0[row]
__global__ void k_pre(const float* __restrict__ input, const float* __restrict__ hidden0,
                      const float* __restrict__ stack, const float* __restrict__ W_ih,
                      const float* __restrict__ b_ih, const float* __restrict__ W_sh,
                      const float* __restrict__ b_sh, float* __restrict__ ws) {
    const int lane = threadIdx.x & 63;
    const int row = blockIdx.x * (blockDim.x >> 6) + (threadIdx.x >> 6);
    if (row >= HID) return;
    float t  = dot4((const float4*)(W_ih + row * VOCABN), (const float4*)input, VOCABN / 4, lane);
    float hb = dot4((const float4*)(W_sh + row * MDIM), (const float4*)stack, MDIM / 4, lane);
    if (lane == 0) {
        ws[WS_TIH + row] = t + b_ih[row];
        ws[WS_HB + row]  = hb + b_sh[row] + hidden0[row];
    }
}

// Kernel B: h[row] = tanh(t_ih[row] + W_hh[row,:]·hidden_bar + b_hh[row])
__global__ void k_h(const float* __restrict__ W_hh, const float* __restrict__ b_hh,
                    float* __restrict__ ws, float* __restrict__ d_out) {
    const int lane = threadIdx.x & 63;
    const int row = blockIdx.x * (blockDim.x >> 6) + (threadIdx.x >> 6);
    if (row >= HID) return;
    float a = dot4((const float4*)(W_hh + row * HID), (const float4*)(ws + WS_HB), HID / 4, lane);
    if (lane == 0) {
        float h = tanhf(ws[WS_TIH + row] + a + b_hh[row]);
        ws[WS_H + row] = h;
        d_out[OUTN + row] = h;  // h is output #1 (after 512 floats of `output`)
    }
}

// Kernel C: output (512), new_elt (128), action softmax (1 wave)
__global__ void k_heads(const float* __restrict__ W_y, const float* __restrict__ b_y,
                        const float* __restrict__ W_n, const float* __restrict__ b_n,
                        const float* __restrict__ W_a, const float* __restrict__ b_a,
                        float* __restrict__ ws, float* __restrict__ d_out) {
    const int lane = threadIdx.x & 63;
    const int row = blockIdx.x * (blockDim.x >> 6) + (threadIdx.x >> 6);
    const float4* h4 = (const float4*)(ws + WS_H);
    if (row < OUTN) {
        float a = dot4((const float4*)(W_y + row * HID), h4, HID / 4, lane);
        if (lane == 0) d_out[row] = 1.f / (1.f + expf(-(a + b_y[row])));
    } else if (row < OUTN + MDIM) {
        const int m = row - OUTN;
        float a = dot4((const float4*)(W_n + m * HID), h4, HID / 4, lane);
        if (lane == 0) ws[WS_NE + m] = 1.f / (1.f + expf(-(a + b_n[m])));
    } else if (row == OUTN + MDIM) {
        float l0 = dot4((const float4*)(W_a), h4, HID / 4, lane);
        float l1 = dot4((const float4*)(W_a + HID), h4, HID / 4, lane);
        if (lane == 0) {
            l0 += b_a[0];
            l1 += b_a[1];
            const float mx = fmaxf(l0, l1);
            const float e0 = expf(l0 - mx), e1 = expf(l1 - mx);
            const float s = e0 + e1;
            ws[WS_AW]     = e0 / s;
            ws[WS_AW + 1] = e1 / s;
        }
    }
}

// Kernel D: new_stack[i] = aw0 * push[i] + aw1 * pop[i]
//   push[0] = new_elt, push[i] = stack[i-1]
//   pop[i]  = stack[i+1], pop[MSIZE-1] = 0
__global__ void k_stack(const float* __restrict__ stack, const float* __restrict__ ws,
                        float* __restrict__ out_stack) {
    const float aw0 = ws[WS_AW];
    const float aw1 = ws[WS_AW + 1];
    const float4* s4  = (const float4*)stack;
    const float4* ne4 = (const float4*)(ws + WS_NE);
    float4* o4 = (float4*)out_stack;
    const int total4 = MSIZE * (MDIM / 4);  // 8,388,608; 32 float4 per row
    for (int e = blockIdx.x * blockDim.x + threadIdx.x; e < total4;
         e += gridDim.x * blockDim.x) {
        const int row = e >> 5;
        float4 push, pop;
        if (row == 0) push = ne4[e & 31];
        else          push = s4[e - 32];
        if (row == MSIZE - 1) pop = make_float4(0.f, 0.f, 0.f, 0.f);
        else                  pop = s4[e + 32];
        float4 r;
        r.x = fmaf(aw0, push.x, aw1 * pop.x);
        r.y = fmaf(aw0, push.y, aw1 * pop.y);
        r.z = fmaf(aw0, push.z, aw1 * pop.z);
        r.w = fmaf(aw0, push.w, aw1 * pop.w);
        o4[e] = r;
    }
}

extern "C" void kernel_launch(void* const* d_in, const int* in_sizes, int n_in,
                              void* d_out, int out_size, void* d_ws, size_t ws_size,
                              hipStream_t stream) {
    const float* input   = (const float*)d_in[0];
    const float* hidden0 = (const float*)d_in[1];
    const float* stack   = (const float*)d_in[2];
    const float* W_ih    = (const float*)d_in[3];
    const float* W_hh    = (const float*)d_in[4];
    const float* b_ih    = (const float*)d_in[5];
    const float* b_hh    = (const float*)d_in[6];
    const float* W_y     = (const float*)d_in[7];
    const float* b_y     = (const float*)d_in[8];
    const float* W_n     = (const float*)d_in[9];
    const float* b_n     = (const float*)d_in[10];
    const float* W_a     = (const float*)d_in[11];
    const float* b_a     = (const float*)d_in[12];
    const float* W_sh    = (const float*)d_in[13];
    const float* b_sh    = (const float*)d_in[14];
    float* out = (float*)d_out;
    float* ws  = (float*)d_ws;

    // A: 1024 rows, 4 waves/block -> 256 blocks
    k_pre<<<256, 256, 0, stream>>>(input, hidden0, stack, W_ih, b_ih, W_sh, b_sh, ws);
    // B: 1024 rows
    k_h<<<256, 256, 0, stream>>>(W_hh, b_hh, ws, out);
    // C: 641 rows -> ceil(641/4) = 161 blocks
    k_heads<<<161, 256, 0, stream>>>(W_y, b_y, W_n, b_n, W_a, b_a, ws, out);
    // D: big streaming blend, grid-stride
    k_stack<<<2048, 256, 0, stream>>>(stack, ws, out + OUTN + HID);
}